// Round 2
// baseline (6920.044 us; speedup 1.0000x reference)
//
#include <hip/hip_runtime.h>
#include <math.h>

#define DIM 384
#define NTRAIN 50000
#define NPATCH 196
#define NROWS_TOT 1568      // 8 * 196
#define K 20
#define NCLS 21
#define RT 8                // rows per block (kernel 1)
#define TC 32               // thread-cols per block
#define CPT 4               // cols per thread per chunk
#define CHUNK 128           // TC * CPT
#define NCHUNKS 391         // ceil(50000 / 128); last chunk has 80 cols
#define NSPLIT 8
#define CPS 49              // chunks per split (last split gets 48)
#define CAND (NSPLIT * K)   // 160 candidates per row
#define RSEL 24             // candidates refined in fp64 (top-24 by fp32, safety margin)

// Branchless sorted-descending top-K insertion, fully static indices (stays in VGPRs).
__device__ __forceinline__ void topk_insert(float (&vals)[K], int (&idxs)[K], float s, int id)
{
    if (s <= vals[K - 1]) return;   // ties keep earlier (lower n) -> matches lax.top_k
    #pragma unroll
    for (int j = K - 1; j >= 1; --j) {
        const bool gt  = s > vals[j];
        const bool gtm = s > vals[j - 1];
        const float nv = gt ? (gtm ? vals[j - 1] : s)  : vals[j];
        const int   ni = gt ? (gtm ? idxs[j - 1] : id) : idxs[j];
        vals[j] = nv;
        idxs[j] = ni;
    }
    const bool gt0 = s > vals[0];
    vals[0] = gt0 ? s  : vals[0];
    idxs[0] = gt0 ? id : idxs[0];
}

__global__ __launch_bounds__(256) void sim_topk_kernel(
    const float* __restrict__ A,       // test_feature, (1568, 384) row-major
    const float* __restrict__ B,       // train_features, (384, 50000) row-major
    float* __restrict__ out_vals,      // (1568, 8, 20)
    int*   __restrict__ out_idx)       // (1568, 8, 20)
{
    __shared__ float As[RT][DIM];          // 12 KB
    __shared__ float mv[RT][TC][K];        // 20 KB
    __shared__ int   mi[RT][TC][K];        // 20 KB

    const int rb = blockIdx.x;             // row tile 0..195
    const int sp = blockIdx.y;             // split 0..7
    const int t  = threadIdx.x;
    const int r  = t >> 5;                 // 0..7 (row within tile)
    const int c  = t & 31;                 // 0..31 (thread-col)

    for (int i = t; i < RT * DIM; i += 256) {
        As[i / DIM][i % DIM] = A[(rb * RT + i / DIM) * DIM + (i % DIM)];
    }
    __syncthreads();

    float vals[K];
    int   idxs[K];
    #pragma unroll
    for (int k = 0; k < K; ++k) { vals[k] = -INFINITY; idxs[k] = -1; }

    const int ch0 = sp * CPS;
    const int ch1 = (ch0 + CPS < NCHUNKS) ? (ch0 + CPS) : NCHUNKS;

    for (int ch = ch0; ch < ch1; ++ch) {
        const int n0 = ch * CHUNK + c * CPT;
        if (n0 >= NTRAIN) continue;        // only final chunk (80 cols, %4==0) is partial
        const float* __restrict__ bcol = B + n0;
        float acc0 = 0.f, acc1 = 0.f, acc2 = 0.f, acc3 = 0.f;
        #pragma unroll 4
        for (int d = 0; d < DIM; ++d) {
            const float a = As[r][d];
            const float4 b4 = *reinterpret_cast<const float4*>(bcol + (size_t)d * NTRAIN);
            acc0 = fmaf(a, b4.x, acc0);
            acc1 = fmaf(a, b4.y, acc1);
            acc2 = fmaf(a, b4.z, acc2);
            acc3 = fmaf(a, b4.w, acc3);
        }
        topk_insert(vals, idxs, acc0, n0 + 0);
        topk_insert(vals, idxs, acc1, n0 + 1);
        topk_insert(vals, idxs, acc2, n0 + 2);
        topk_insert(vals, idxs, acc3, n0 + 3);
    }

    #pragma unroll
    for (int k = 0; k < K; ++k) { mv[r][c][k] = vals[k]; mi[r][c][k] = idxs[k]; }
    __syncthreads();

    // Merge 32 sorted lists per row. 4 waves; each wave handles 2 rows (one per 32-lane half).
    const int wave = t >> 6;
    const int lane = t & 63;
    const int half = lane >> 5;
    const int lc   = lane & 31;
    const int mr   = wave * 2 + half;

    int ptr = 0;
    for (int round = 0; round < K; ++round) {
        float hv = (ptr < K) ? mv[mr][lc][ptr] : -INFINITY;
        int   hi = (ptr < K) ? mi[mr][lc][ptr] : -1;
        int   hl = lc;
        #pragma unroll
        for (int off = 16; off >= 1; off >>= 1) {
            const float ov = __shfl_xor(hv, off, 32);
            const int   oi = __shfl_xor(hi, off, 32);
            const int   ol = __shfl_xor(hl, off, 32);
            if (ov > hv || (ov == hv && (unsigned)oi < (unsigned)hi)) { hv = ov; hi = oi; hl = ol; }
        }
        if (lc == hl) ptr++;
        if (lc == 0) {
            const int o = ((rb * RT + mr) * NSPLIT + sp) * K + round;
            out_vals[o] = hv;
            out_idx[o]  = hi;
        }
    }
}

__global__ __launch_bounds__(256) void vote_kernel(
    const float* __restrict__ cvals,   // (1568, 160) fp32 candidate values
    const int*   __restrict__ cidx,    // (1568, 160) candidate train indices
    const float* __restrict__ A,       // test_feature, (1568, 384)
    const float* __restrict__ B,       // train_features, (384, 50000)
    const int*   __restrict__ labels,  // (256, 50000)
    int*         __restrict__ out)     // (8, 224, 224)
{
    __shared__ float  sv[CAND];
    __shared__ int    si[CAND];
    __shared__ float  Arow[DIM];
    __shared__ int    sel_i[RSEL];         // train idx of fp32-top-24, sorted by fp32 rank
    __shared__ double cpart[RSEL][8];      // fp64 partial dots
    __shared__ double dv[RSEL];            // fp64 refined values
    __shared__ double tvd[K];              // fp64 top-20 values, sorted desc
    __shared__ int    ti[K];               // their train indices
    __shared__ double w[K];                // softmax weights

    const int gr = blockIdx.x;             // global row 0..1567
    const int t  = threadIdx.x;            // 0..255 (doubles as pixel-in-patch)

    for (int i = t; i < DIM; i += 256) Arow[i] = A[(size_t)gr * DIM + i];
    if (t < CAND) {
        sv[t] = cvals[gr * CAND + t];
        si[t] = cidx[gr * CAND + t];
    }
    __syncthreads();

    // fp32 rank selection: top-RSEL of 160 (total order: val desc, idx asc).
    if (t < CAND) {
        const float v = sv[t];
        const unsigned id = (unsigned)si[t];
        int rank = 0;
        for (int j = 0; j < CAND; ++j) {
            const float vj = sv[j];
            const unsigned ij = (unsigned)si[j];
            if (vj > v || (vj == v && ij < id)) rank++;
        }
        if (rank < RSEL) sel_i[rank] = (int)id;
    }
    __syncthreads();

    // fp64 recompute of the 24 selected dot products. 8 threads per candidate.
    if (t < RSEL * 8) {
        const int cand = t >> 3;
        const int part = t & 7;
        const int idx  = sel_i[cand];
        const int d0   = part * (DIM / 8);      // 48 dims each
        double acc = 0.0;
        #pragma unroll 4
        for (int d = d0; d < d0 + DIM / 8; ++d) {
            acc = fma((double)Arow[d], (double)B[(size_t)d * NTRAIN + idx], acc);
        }
        cpart[cand][part] = acc;
    }
    __syncthreads();

    if (t < RSEL) {
        double s = 0.0;
        #pragma unroll
        for (int p = 0; p < 8; ++p) s += cpart[t][p];
        dv[t] = s;
    }
    __syncthreads();

    // fp64 re-rank: top-20 of 24 (val desc, idx asc).
    if (t < RSEL) {
        const double v = dv[t];
        const unsigned id = (unsigned)sel_i[t];
        int rank = 0;
        for (int j = 0; j < RSEL; ++j) {
            const double vj = dv[j];
            const unsigned ij = (unsigned)sel_i[j];
            if (vj > v || (vj == v && ij < id)) rank++;
        }
        if (rank < K) { tvd[rank] = v; ti[rank] = (int)id; }
    }
    __syncthreads();

    // fp64 softmax over the sorted top-20.
    if (t == 0) {
        const double m = tvd[0];
        double e[K];
        double s = 0.0;
        #pragma unroll
        for (int k = 0; k < K; ++k) { e[k] = exp(tvd[k] - m); s += e[k]; }
        const double inv = 1.0 / s;
        #pragma unroll
        for (int k = 0; k < K; ++k) w[k] = e[k] * inv;
    }
    __syncthreads();

    // Per-pixel label gather + fp64 weighted vote + argmax.
    int lbl[K];
    #pragma unroll
    for (int k = 0; k < K; ++k) lbl[k] = labels[(size_t)t * NTRAIN + ti[k]];

    double v[NCLS];
    #pragma unroll
    for (int c = 0; c < NCLS; ++c) v[c] = 0.0;
    #pragma unroll
    for (int k = 0; k < K; ++k) {
        const double wk = w[k];
        const int    lk = lbl[k];
        #pragma unroll
        for (int c = 0; c < NCLS; ++c) v[c] += (lk == c) ? wk : 0.0;
    }

    double best = v[0];
    int bi = 0;
    #pragma unroll
    for (int c = 1; c < NCLS; ++c) {
        if (v[c] > best) { best = v[c]; bi = c; }   // strict > : first max, like np.argmax
    }

    const int b  = gr / NPATCH;
    const int p  = gr % NPATCH;
    const int pr = p / 14, pc = p % 14;
    const int i  = t >> 4, j = t & 15;
    out[b * (224 * 224) + (pr * 16 + i) * 224 + (pc * 16 + j)] = bi;
}

extern "C" void kernel_launch(void* const* d_in, const int* in_sizes, int n_in,
                              void* d_out, int out_size, void* d_ws, size_t ws_size,
                              hipStream_t stream)
{
    const float* test_feature   = (const float*)d_in[0];  // (8, 196, 384)
    const float* train_features = (const float*)d_in[1];  // (384, 50000)
    const int*   train_labels   = (const int*)d_in[2];    // (256, 50000)
    int*         out            = (int*)d_out;            // (8, 224, 224) int32

    float* ws_vals = (float*)d_ws;                                    // 1568*160 floats
    int*   ws_idx  = (int*)((char*)d_ws + (size_t)NROWS_TOT * CAND * sizeof(float));

    sim_topk_kernel<<<dim3(NROWS_TOT / RT, NSPLIT), 256, 0, stream>>>(
        test_feature, train_features, ws_vals, ws_idx);

    vote_kernel<<<NROWS_TOT, 256, 0, stream>>>(
        ws_vals, ws_idx, test_feature, train_features, train_labels, out);
}

// Round 3
// 2628.791 us; speedup vs baseline: 2.6324x; 2.6324x over previous
//
#include <hip/hip_runtime.h>
#include <math.h>

#define DIM 384
#define NTRAIN 50000
#define NPATCH 196
#define NROWS_TOT 1568      // 8 * 196
#define K 20
#define NCLS 21
#define M 32                // rows per block (kernel 1)
#define NT 128              // cols per chunk
#define BK 64               // K-step depth
#define KSTEPS 6            // 384 / 64
#define NCHUNKS 391         // ceil(50000/128), last chunk 80 cols
#define NSPLIT 16           // chunk ch -> split ch%16
#define CAND (NSPLIT * K)   // 320 candidates per row
#define RSEL 24             // fp64-refined candidates

// Branchless sorted-descending top-K insertion (static indices -> stays in VGPRs).
__device__ __forceinline__ void topk_insert(float (&vals)[K], int (&idxs)[K], float s, int id)
{
    if (s <= vals[K - 1]) return;   // ties keep earlier (lower col) -> matches lax.top_k
    #pragma unroll
    for (int j = K - 1; j >= 1; --j) {
        const bool gt  = s > vals[j];
        const bool gtm = s > vals[j - 1];
        const float nv = gt ? (gtm ? vals[j - 1] : s)  : vals[j];
        const int   ni = gt ? (gtm ? idxs[j - 1] : id) : idxs[j];
        vals[j] = nv;
        idxs[j] = ni;
    }
    const bool gt0 = s > vals[0];
    vals[0] = gt0 ? s  : vals[0];
    idxs[0] = gt0 ? id : idxs[0];
}

__device__ __forceinline__ void prefetch_tiles(
    const float* __restrict__ A, const float* __restrict__ B,
    int r0, int ch, int ks, int t, bool valid,
    float4 (&pb)[8], float4 (&pa)[2])
{
    if (!valid) return;
    const int k0 = ks * BK;
    const int n0 = ch * NT;
    #pragma unroll
    for (int q = 0; q < 8; ++q) {
        const int id = q * 256 + t;
        const int kk = id >> 5;          // 0..63
        const int nq = id & 31;          // 0..31
        const int col = n0 + nq * 4;
        if (col < NTRAIN) {              // NTRAIN%4==0 -> float4 fully valid or fully OOB
            pb[q] = *reinterpret_cast<const float4*>(B + (size_t)(k0 + kk) * NTRAIN + col);
        } else {
            pb[q] = make_float4(0.f, 0.f, 0.f, 0.f);
        }
    }
    #pragma unroll
    for (int q = 0; q < 2; ++q) {
        const int id = q * 256 + t;
        const int ar = id >> 4;          // 0..31
        const int kq = id & 15;          // 0..15
        pa[q] = *reinterpret_cast<const float4*>(A + (size_t)(r0 + ar) * DIM + k0 + kq * 4);
    }
}

// LDS layout (57856 B, 2 blocks/CU):
//   [0      , 32768): Bs[64][128] float        (GEMM phase)
//   [32768  , 40960): As[64][32]  float (transposed A-tile)
//   [40960  , 57856): Cs[32][132] float (padded C-tile)
//   merge phase aliases [0,40960) as mv[32*8*20] float + mi[32*8*20] int
__global__ __launch_bounds__(256, 2) void sim_topk_kernel(
    const float* __restrict__ A,       // (1568, 384)
    const float* __restrict__ B,       // (384, 50000)
    float* __restrict__ out_vals,      // (1568, 16, 20)
    int*   __restrict__ out_idx)       // (1568, 16, 20)
{
    __shared__ __align__(16) char smem[57856];
    float* Bs = reinterpret_cast<float*>(smem);
    float* As = reinterpret_cast<float*>(smem + 32768);
    float* Cs = reinterpret_cast<float*>(smem + 40960);
    float* mv = reinterpret_cast<float*>(smem);
    int*   mi = reinterpret_cast<int*>(smem + 20480);

    const int t  = threadIdx.x;
    const int r0 = blockIdx.x * M;
    const int sp = blockIdx.y;
    const int ty = t >> 5;             // 0..7  -> rows ty*4..+3
    const int tx = t & 31;             // 0..31 -> cols tx*4..+3
    const int row = t >> 3;            // scan phase: 0..31
    const int seg = t & 7;             // scan phase: col = seg + 8*i

    float vals[K];
    int   idxs[K];
    #pragma unroll
    for (int k = 0; k < K; ++k) { vals[k] = -INFINITY; idxs[k] = -1; }

    const int nch = (NCHUNKS - sp + NSPLIT - 1) / NSPLIT;   // 25 (sp<=6) or 24

    float4 pb[8], pa[2];
    prefetch_tiles(A, B, r0, sp, 0, t, true, pb, pa);

    for (int ci = 0; ci < nch; ++ci) {
        const int ch = sp + NSPLIT * ci;
        float acc[4][4];
        #pragma unroll
        for (int i = 0; i < 4; ++i)
            #pragma unroll
            for (int j = 0; j < 4; ++j) acc[i][j] = 0.f;

        for (int ks = 0; ks < KSTEPS; ++ks) {
            __syncthreads();           // previous compute/scans done with LDS
            // commit prefetched tiles to LDS
            #pragma unroll
            for (int q = 0; q < 8; ++q) {
                const int id = q * 256 + t;
                const int kk = id >> 5;
                const int nq = id & 31;
                *reinterpret_cast<float4*>(&Bs[kk * NT + nq * 4]) = pb[q];
            }
            #pragma unroll
            for (int q = 0; q < 2; ++q) {
                const int id = q * 256 + t;
                const int ar = id >> 4;
                const int kq = id & 15;
                As[(kq * 4 + 0) * M + ar] = pa[q].x;
                As[(kq * 4 + 1) * M + ar] = pa[q].y;
                As[(kq * 4 + 2) * M + ar] = pa[q].z;
                As[(kq * 4 + 3) * M + ar] = pa[q].w;
            }
            __syncthreads();
            // prefetch next K-step (or next chunk's first) while computing
            int nks = ks + 1, nci = ci;
            if (nks == KSTEPS) { nks = 0; nci = ci + 1; }
            prefetch_tiles(A, B, r0, sp + NSPLIT * nci, nks, t, nci < nch, pb, pa);

            #pragma unroll 8
            for (int kk = 0; kk < BK; ++kk) {
                const float4 a4 = *reinterpret_cast<const float4*>(&As[kk * M + ty * 4]);
                const float4 b4 = *reinterpret_cast<const float4*>(&Bs[kk * NT + tx * 4]);
                acc[0][0] = fmaf(a4.x, b4.x, acc[0][0]);
                acc[0][1] = fmaf(a4.x, b4.y, acc[0][1]);
                acc[0][2] = fmaf(a4.x, b4.z, acc[0][2]);
                acc[0][3] = fmaf(a4.x, b4.w, acc[0][3]);
                acc[1][0] = fmaf(a4.y, b4.x, acc[1][0]);
                acc[1][1] = fmaf(a4.y, b4.y, acc[1][1]);
                acc[1][2] = fmaf(a4.y, b4.z, acc[1][2]);
                acc[1][3] = fmaf(a4.y, b4.w, acc[1][3]);
                acc[2][0] = fmaf(a4.z, b4.x, acc[2][0]);
                acc[2][1] = fmaf(a4.z, b4.y, acc[2][1]);
                acc[2][2] = fmaf(a4.z, b4.z, acc[2][2]);
                acc[2][3] = fmaf(a4.z, b4.w, acc[2][3]);
                acc[3][0] = fmaf(a4.w, b4.x, acc[3][0]);
                acc[3][1] = fmaf(a4.w, b4.y, acc[3][1]);
                acc[3][2] = fmaf(a4.w, b4.z, acc[3][2]);
                acc[3][3] = fmaf(a4.w, b4.w, acc[3][3]);
            }
        }

        // C-tile -> LDS (padded stride 132), then per-row strided top-k scan
        #pragma unroll
        for (int i = 0; i < 4; ++i) {
            const float4 cv = make_float4(acc[i][0], acc[i][1], acc[i][2], acc[i][3]);
            *reinterpret_cast<float4*>(&Cs[(ty * 4 + i) * 132 + tx * 4]) = cv;
        }
        __syncthreads();
        const int n0 = ch * NT;
        #pragma unroll
        for (int i = 0; i < 16; ++i) {
            const int coff = seg + 8 * i;          // strided -> conflict-free Cs reads
            const int col  = n0 + coff;
            const float s  = Cs[row * 132 + coff];
            if (col < NTRAIN) topk_insert(vals, idxs, s, col);
        }
    }

    // merge 8 sorted lists per row -> split top-20
    __syncthreads();                   // done with Bs/As before aliasing
    #pragma unroll
    for (int k = 0; k < K; ++k) {
        mv[(row * 8 + seg) * K + k] = vals[k];
        mi[(row * 8 + seg) * K + k] = idxs[k];
    }
    __syncthreads();

    int ptr = 0;
    const int gr = r0 + row;
    for (int round = 0; round < K; ++round) {
        float hv = (ptr < K) ? mv[(row * 8 + seg) * K + ptr] : -INFINITY;
        int   hi = (ptr < K) ? mi[(row * 8 + seg) * K + ptr] : -1;
        int   hl = seg;
        #pragma unroll
        for (int off = 4; off >= 1; off >>= 1) {
            const float ov = __shfl_xor(hv, off, 8);
            const int   oi = __shfl_xor(hi, off, 8);
            const int   ol = __shfl_xor(hl, off, 8);
            if (ov > hv || (ov == hv && (unsigned)oi < (unsigned)hi)) { hv = ov; hi = oi; hl = ol; }
        }
        if (seg == hl) ptr++;
        if (seg == 0) {
            const int o = (gr * NSPLIT + sp) * K + round;
            out_vals[o] = hv;
            out_idx[o]  = hi;
        }
    }
}

__global__ __launch_bounds__(256) void vote_kernel(
    const float* __restrict__ cvals,   // (1568, 320)
    const int*   __restrict__ cidx,    // (1568, 320)
    const float* __restrict__ A,       // (1568, 384)
    const float* __restrict__ B,       // (384, 50000)
    const int*   __restrict__ labels,  // (256, 50000)
    int*         __restrict__ out)     // (8, 224, 224)
{
    __shared__ float  sv[CAND];
    __shared__ int    si[CAND];
    __shared__ float  Arow[DIM];
    __shared__ int    sel_i[RSEL];
    __shared__ double cpart[RSEL][8];
    __shared__ double dv[RSEL];
    __shared__ double tvd[K];
    __shared__ int    ti[K];
    __shared__ double w[K];

    const int gr = blockIdx.x;
    const int t  = threadIdx.x;

    for (int i = t; i < DIM; i += 256) Arow[i] = A[(size_t)gr * DIM + i];
    for (int e = t; e < CAND; e += 256) {
        sv[e] = cvals[gr * CAND + e];
        si[e] = cidx[gr * CAND + e];
    }
    __syncthreads();

    // fp32 rank selection: top-RSEL of 320 (val desc, idx asc).
    for (int e = t; e < CAND; e += 256) {
        const float v = sv[e];
        const unsigned id = (unsigned)si[e];
        int rank = 0;
        for (int j = 0; j < CAND; ++j) {
            const float vj = sv[j];
            const unsigned ij = (unsigned)si[j];
            if (vj > v || (vj == v && ij < id)) rank++;
        }
        if (rank < RSEL) sel_i[rank] = (int)id;
    }
    __syncthreads();

    // fp64 recompute of selected dot products; 8 threads per candidate.
    if (t < RSEL * 8) {
        const int cand = t >> 3;
        const int part = t & 7;
        const int idx  = sel_i[cand];
        const int d0   = part * (DIM / 8);
        double acc = 0.0;
        #pragma unroll 8
        for (int d = d0; d < d0 + DIM / 8; ++d) {
            acc = fma((double)Arow[d], (double)B[(size_t)d * NTRAIN + idx], acc);
        }
        cpart[cand][part] = acc;
    }
    __syncthreads();

    if (t < RSEL) {
        double s = 0.0;
        #pragma unroll
        for (int p = 0; p < 8; ++p) s += cpart[t][p];
        dv[t] = s;
    }
    __syncthreads();

    // fp64 re-rank: top-20 of 24.
    if (t < RSEL) {
        const double v = dv[t];
        const unsigned id = (unsigned)sel_i[t];
        int rank = 0;
        for (int j = 0; j < RSEL; ++j) {
            const double vj = dv[j];
            const unsigned ij = (unsigned)sel_i[j];
            if (vj > v || (vj == v && ij < id)) rank++;
        }
        if (rank < K) { tvd[rank] = v; ti[rank] = (int)id; }
    }
    __syncthreads();

    if (t == 0) {
        const double m = tvd[0];
        double e[K];
        double s = 0.0;
        #pragma unroll
        for (int k = 0; k < K; ++k) { e[k] = exp(tvd[k] - m); s += e[k]; }
        const double inv = 1.0 / s;
        #pragma unroll
        for (int k = 0; k < K; ++k) w[k] = e[k] * inv;
    }
    __syncthreads();

    int lbl[K];
    #pragma unroll
    for (int k = 0; k < K; ++k) lbl[k] = labels[(size_t)t * NTRAIN + ti[k]];

    double v[NCLS];
    #pragma unroll
    for (int c = 0; c < NCLS; ++c) v[c] = 0.0;
    #pragma unroll
    for (int k = 0; k < K; ++k) {
        const double wk = w[k];
        const int    lk = lbl[k];
        #pragma unroll
        for (int c = 0; c < NCLS; ++c) v[c] += (lk == c) ? wk : 0.0;
    }

    double best = v[0];
    int bi = 0;
    #pragma unroll
    for (int c = 1; c < NCLS; ++c) {
        if (v[c] > best) { best = v[c]; bi = c; }
    }

    const int b  = gr / NPATCH;
    const int p  = gr % NPATCH;
    const int pr = p / 14, pc = p % 14;
    const int i  = t >> 4, j = t & 15;
    out[b * (224 * 224) + (pr * 16 + i) * 224 + (pc * 16 + j)] = bi;
}

extern "C" void kernel_launch(void* const* d_in, const int* in_sizes, int n_in,
                              void* d_out, int out_size, void* d_ws, size_t ws_size,
                              hipStream_t stream)
{
    const float* test_feature   = (const float*)d_in[0];  // (8, 196, 384)
    const float* train_features = (const float*)d_in[1];  // (384, 50000)
    const int*   train_labels   = (const int*)d_in[2];    // (256, 50000)
    int*         out            = (int*)d_out;            // (8, 224, 224) int32

    float* ws_vals = (float*)d_ws;                                    // 1568*320 floats
    int*   ws_idx  = (int*)((char*)d_ws + (size_t)NROWS_TOT * CAND * sizeof(float));

    sim_topk_kernel<<<dim3(NROWS_TOT / M, NSPLIT), 256, 0, stream>>>(
        test_feature, train_features, ws_vals, ws_idx);

    vote_kernel<<<NROWS_TOT, 256, 0, stream>>>(
        ws_vals, ws_idx, test_feature, train_features, train_labels, out);
}

// Round 4
// 1205.216 us; speedup vs baseline: 5.7417x; 2.1812x over previous
//
#include <hip/hip_runtime.h>
#include <math.h>

#define DIM 384
#define NTRAIN 50000
#define NPATCH 196
#define NROWS_TOT 1568
#define WSROWS 1600         // 25 tiles * 64 rows (rows >=1568 are clamped duplicates)
#define K 20
#define NCLS 21
#define MROWS 64            // rows per block
#define NT 128              // cols per chunk
#define BK 32               // k per stage
#define NSTAGE 12           // 384/32
#define NCHUNKS 391         // ceil(50000/128)
#define NSPLIT 20
#define NTILES 25           // ceil(1568/64)
#define CAND (NSPLIT * K)   // 400 candidates per row
#define RSEL 32             // fp64-refined candidates (32*8 = 256 threads)

// LDS layout (bytes). Strides chosen: 40 bf16 = 80 B rows -> b128 frags 16B-aligned,
// <=2-way banks (with B k-XOR-swizzle). Cs stride 132 floats -> 2-way.
#define A_STRIDE 40
#define B_STRIDE 40
#define CS_STRIDE 132
#define AS_H_OFF 0
#define AS_L_OFF 5120
#define BS_H_OFF 10240
#define BS_L_OFF 20480
#define CS_OFF   30720
#define SMEM_BYTES 64512    // 30720 + 64*132*4 = 64512 < 64 KiB

typedef __attribute__((ext_vector_type(8))) short bf16x8;  // 8 bf16 (4 VGPRs)
typedef __attribute__((ext_vector_type(4))) float f32x4;

__device__ __forceinline__ unsigned pack2bf(float f0, float f1) {
    // [bf16(f1) : bf16(f0)] by truncation; lo-plane captures the residual.
    return (__float_as_uint(f0) >> 16) | (__float_as_uint(f1) & 0xFFFF0000u);
}

// Branchless sorted-descending top-K insertion (static indices -> stays in VGPRs).
__device__ __forceinline__ void topk_insert(float (&vals)[K], int (&idxs)[K], float s, int id)
{
    if (s <= vals[K - 1]) return;   // ties keep earlier (lower col) -> matches lax.top_k
    #pragma unroll
    for (int j = K - 1; j >= 1; --j) {
        const bool gt  = s > vals[j];
        const bool gtm = s > vals[j - 1];
        const float nv = gt ? (gtm ? vals[j - 1] : s)  : vals[j];
        const int   ni = gt ? (gtm ? idxs[j - 1] : id) : idxs[j];
        vals[j] = nv;
        idxs[j] = ni;
    }
    const bool gt0 = s > vals[0];
    vals[0] = gt0 ? s  : vals[0];
    idxs[0] = gt0 ? id : idxs[0];
}

__global__ __launch_bounds__(256, 2) void sim_topk_kernel(
    const float* __restrict__ A,       // (1568, 384)
    const float* __restrict__ B,       // (384, 50000)
    float* __restrict__ out_vals,      // (1600, 20, 20)
    int*   __restrict__ out_idx)
{
    __shared__ __align__(16) char smem[SMEM_BYTES];
    short* as_h = (short*)(smem + AS_H_OFF);   // [64][40] bf16, A[m][k]
    short* as_l = (short*)(smem + AS_L_OFF);
    short* bs_h = (short*)(smem + BS_H_OFF);   // [128][40] bf16, B^T[n][k^swz]
    short* bs_l = (short*)(smem + BS_L_OFF);
    float* Cs   = (float*)(smem + CS_OFF);     // [64][132]

    const int t  = threadIdx.x;
    const int r0 = blockIdx.x * MROWS;
    const int sp = blockIdx.y;
    const int w  = t >> 6;             // wave 0..3
    const int l  = t & 63;
    const int wn = w * 32;             // wave n-offset (64m x 32n per wave)
    const int lm = l & 15;
    const int lq = l >> 4;

    // A staging: thread -> (row 0..63, k-group of 8)
    const int a_row = t >> 2;
    const int a_dg  = (t & 3) * 8;
    const int a_r   = (r0 + a_row < NROWS_TOT) ? (r0 + a_row) : (NROWS_TOT - 1);
    // B staging: thread -> (n 0..127, k-slots {b_ks0, b_ks0+2} of 8)
    const int b_n   = t & 127;
    const int b_ks0 = t >> 7;
    const int b_sw  = ((b_n >> 3) & 3) * 8;    // XOR swizzle breaks write conflicts

    // scan: thread -> (row 0..63, col quarter 0..3)
    const int s_row = t >> 2;
    const int s_seg = t & 3;

    const int nch = (NCHUNKS - sp + NSPLIT - 1) / NSPLIT;

    float vals[K]; int idxs[K];
    #pragma unroll
    for (int k = 0; k < K; ++k) { vals[k] = -INFINITY; idxs[k] = -1; }

    float pa[8];
    float pb[2][8];

    auto prefetch = [&](int ci, int ks) {
        if (ci >= nch) return;
        const int kb = ks * BK;
        const float* ap = A + (size_t)a_r * DIM + kb + a_dg;
        const float4 t0 = *(const float4*)(ap);
        const float4 t1 = *(const float4*)(ap + 4);
        pa[0]=t0.x; pa[1]=t0.y; pa[2]=t0.z; pa[3]=t0.w;
        pa[4]=t1.x; pa[5]=t1.y; pa[6]=t1.z; pa[7]=t1.w;
        const int n = (sp + NSPLIT * ci) * NT + b_n;
        const bool v = (n < NTRAIN);
        #pragma unroll
        for (int u = 0; u < 2; ++u) {
            const int kr = kb + (b_ks0 + 2*u) * 8;
            #pragma unroll
            for (int j = 0; j < 8; ++j)
                pb[u][j] = v ? B[(size_t)(kr + j) * NTRAIN + n] : 0.0f;
        }
    };

    auto cvt8 = [&](const float* f, uint4& hi, uint4& lo) {
        float r[8];
        #pragma unroll
        for (int j = 0; j < 8; ++j) {
            const unsigned b = __float_as_uint(f[j]) & 0xFFFF0000u;
            r[j] = f[j] - __uint_as_float(b);      // exact residual
        }
        hi.x = pack2bf(f[0], f[1]); hi.y = pack2bf(f[2], f[3]);
        hi.z = pack2bf(f[4], f[5]); hi.w = pack2bf(f[6], f[7]);
        lo.x = pack2bf(r[0], r[1]); lo.y = pack2bf(r[2], r[3]);
        lo.z = pack2bf(r[4], r[5]); lo.w = pack2bf(r[6], r[7]);
    };

    auto commit = [&]() {
        uint4 hi, lo;
        cvt8(pa, hi, lo);
        *(uint4*)(as_h + a_row * A_STRIDE + a_dg) = hi;
        *(uint4*)(as_l + a_row * A_STRIDE + a_dg) = lo;
        #pragma unroll
        for (int u = 0; u < 2; ++u) {
            cvt8(pb[u], hi, lo);
            const int koff = (((b_ks0 + 2*u) * 8) ^ b_sw);
            *(uint4*)(bs_h + b_n * B_STRIDE + koff) = hi;
            *(uint4*)(bs_l + b_n * B_STRIDE + koff) = lo;
        }
    };

    prefetch(0, 0);

    for (int ci = 0; ci < nch; ++ci) {
        const int ch = sp + NSPLIT * ci;
        f32x4 acc[4][2];
        #pragma unroll
        for (int im = 0; im < 4; ++im)
            #pragma unroll
            for (int in_ = 0; in_ < 2; ++in_)
                acc[im][in_] = (f32x4){0.f, 0.f, 0.f, 0.f};

        for (int ks = 0; ks < NSTAGE; ++ks) {
            __syncthreads();               // prev frag reads / scan done
            commit();
            __syncthreads();
            int nks = ks + 1, nci = ci;
            if (nks == NSTAGE) { nks = 0; nci = ci + 1; }
            prefetch(nci, nks);            // hide global latency behind mfma

            bf16x8 af[4][2], bf[2][2];
            #pragma unroll
            for (int im = 0; im < 4; ++im) {
                const int ao = (im * 16 + lm) * A_STRIDE + lq * 8;
                af[im][0] = *(const bf16x8*)(as_h + ao);
                af[im][1] = *(const bf16x8*)(as_l + ao);
            }
            #pragma unroll
            for (int in_ = 0; in_ < 2; ++in_) {
                const int nloc = wn + in_ * 16 + lm;
                const int bo = nloc * B_STRIDE + ((lq * 8) ^ (((nloc >> 3) & 3) * 8));
                bf[in_][0] = *(const bf16x8*)(bs_h + bo);
                bf[in_][1] = *(const bf16x8*)(bs_l + bo);
            }
            #pragma unroll
            for (int im = 0; im < 4; ++im) {
                #pragma unroll
                for (int in_ = 0; in_ < 2; ++in_) {
                    acc[im][in_] = __builtin_amdgcn_mfma_f32_16x16x32_bf16(af[im][0], bf[in_][0], acc[im][in_], 0, 0, 0);
                    acc[im][in_] = __builtin_amdgcn_mfma_f32_16x16x32_bf16(af[im][0], bf[in_][1], acc[im][in_], 0, 0, 0);
                    acc[im][in_] = __builtin_amdgcn_mfma_f32_16x16x32_bf16(af[im][1], bf[in_][0], acc[im][in_], 0, 0, 0);
                }
            }
        }

        // C-frag -> Cs (C/D: col=l&15, row=(l>>4)*4+reg; verified m89/m91)
        #pragma unroll
        for (int im = 0; im < 4; ++im)
            #pragma unroll
            for (int in_ = 0; in_ < 2; ++in_)
                #pragma unroll
                for (int r = 0; r < 4; ++r)
                    Cs[(im * 16 + lq * 4 + r) * CS_STRIDE + wn + in_ * 16 + lm] = acc[im][in_][r];
        __syncthreads();

        const int n0 = ch * NT;
        #pragma unroll
        for (int i = 0; i < 32; ++i) {
            const int coff = s_seg + 4 * i;
            const int col  = n0 + coff;
            const float s  = Cs[s_row * CS_STRIDE + coff];
            if (col < NTRAIN) topk_insert(vals, idxs, s, col);
        }
        // next iteration's leading __syncthreads() fences scan vs. As/Bs commit
    }

    // merge 4 sorted per-quarter lists per row (width-4 shuffle tournament,
    // static list shift -> no LDS, no dynamic register indexing)
    const int gr = r0 + s_row;
    for (int round = 0; round < K; ++round) {
        float hv = vals[0]; int hi = idxs[0]; int hl = s_seg;
        #pragma unroll
        for (int off = 2; off >= 1; off >>= 1) {
            const float ov = __shfl_xor(hv, off, 4);
            const int   oi = __shfl_xor(hi, off, 4);
            const int   ol = __shfl_xor(hl, off, 4);
            if (ov > hv || (ov == hv && (unsigned)oi < (unsigned)hi)) { hv = ov; hi = oi; hl = ol; }
        }
        const bool won = (hl == s_seg);
        #pragma unroll
        for (int j = 0; j < K - 1; ++j) {
            vals[j] = won ? vals[j + 1] : vals[j];
            idxs[j] = won ? idxs[j + 1] : idxs[j];
        }
        if (won) vals[K - 1] = -INFINITY;
        if (s_seg == 0) {
            const int o = (gr * NSPLIT + sp) * K + round;
            out_vals[o] = hv;
            out_idx[o]  = hi;
        }
    }
}

__global__ __launch_bounds__(256) void vote_kernel(
    const float* __restrict__ cvals,   // (1600, 400)
    const int*   __restrict__ cidx,
    const float* __restrict__ A,       // (1568, 384)
    const float* __restrict__ B,       // (384, 50000)
    const int*   __restrict__ labels,  // (256, 50000)
    int*         __restrict__ out)     // (8, 224, 224)
{
    __shared__ float  sv[CAND];
    __shared__ int    si[CAND];
    __shared__ float  Arow[DIM];
    __shared__ int    sel_i[RSEL];
    __shared__ double cpart[RSEL][8];
    __shared__ double dv[RSEL];
    __shared__ double tvd[K];
    __shared__ int    ti[K];
    __shared__ double wgt[K];

    const int gr = blockIdx.x;
    const int t  = threadIdx.x;

    for (int i = t; i < DIM; i += 256) Arow[i] = A[(size_t)gr * DIM + i];
    for (int e = t; e < CAND; e += 256) {
        sv[e] = cvals[gr * CAND + e];
        si[e] = cidx[gr * CAND + e];
    }
    __syncthreads();

    // approx-value rank selection: top-RSEL of 400 (val desc, idx asc)
    for (int e = t; e < CAND; e += 256) {
        const float v = sv[e];
        const unsigned id = (unsigned)si[e];
        int rank = 0;
        for (int j = 0; j < CAND; ++j) {
            const float vj = sv[j];
            const unsigned ij = (unsigned)si[j];
            if (vj > v || (vj == v && ij < id)) rank++;
        }
        if (rank < RSEL) sel_i[rank] = (int)id;
    }
    __syncthreads();

    // fp64 recompute of selected dot products; 8 threads per candidate.
    {
        const int cand = t >> 3;
        const int part = t & 7;
        const int idx  = sel_i[cand];
        const int d0   = part * (DIM / 8);
        double acc = 0.0;
        #pragma unroll 8
        for (int d = d0; d < d0 + DIM / 8; ++d) {
            acc = fma((double)Arow[d], (double)B[(size_t)d * NTRAIN + idx], acc);
        }
        cpart[cand][part] = acc;
    }
    __syncthreads();

    if (t < RSEL) {
        double s = 0.0;
        #pragma unroll
        for (int p = 0; p < 8; ++p) s += cpart[t][p];
        dv[t] = s;
    }
    __syncthreads();

    // fp64 re-rank: top-20 of 32
    if (t < RSEL) {
        const double v = dv[t];
        const unsigned id = (unsigned)sel_i[t];
        int rank = 0;
        for (int j = 0; j < RSEL; ++j) {
            const double vj = dv[j];
            const unsigned ij = (unsigned)sel_i[j];
            if (vj > v || (vj == v && ij < id)) rank++;
        }
        if (rank < K) { tvd[rank] = v; ti[rank] = (int)id; }
    }
    __syncthreads();

    if (t == 0) {
        const double m = tvd[0];
        double e[K];
        double s = 0.0;
        #pragma unroll
        for (int k = 0; k < K; ++k) { e[k] = exp(tvd[k] - m); s += e[k]; }
        const double inv = 1.0 / s;
        #pragma unroll
        for (int k = 0; k < K; ++k) wgt[k] = e[k] * inv;
    }
    __syncthreads();

    int lbl[K];
    #pragma unroll
    for (int k = 0; k < K; ++k) lbl[k] = labels[(size_t)t * NTRAIN + ti[k]];

    double v[NCLS];
    #pragma unroll
    for (int c = 0; c < NCLS; ++c) v[c] = 0.0;
    #pragma unroll
    for (int k = 0; k < K; ++k) {
        const double wk = wgt[k];
        const int    lk = lbl[k];
        #pragma unroll
        for (int c = 0; c < NCLS; ++c) v[c] += (lk == c) ? wk : 0.0;
    }

    double best = v[0];
    int bi = 0;
    #pragma unroll
    for (int c = 1; c < NCLS; ++c) {
        if (v[c] > best) { best = v[c]; bi = c; }   // strict > : first max, like np.argmax
    }

    const int b  = gr / NPATCH;
    const int p  = gr % NPATCH;
    const int pr = p / 14, pc = p % 14;
    const int i  = t >> 4, j = t & 15;
    out[b * (224 * 224) + (pr * 16 + i) * 224 + (pc * 16 + j)] = bi;
}

extern "C" void kernel_launch(void* const* d_in, const int* in_sizes, int n_in,
                              void* d_out, int out_size, void* d_ws, size_t ws_size,
                              hipStream_t stream)
{
    const float* test_feature   = (const float*)d_in[0];  // (8, 196, 384)
    const float* train_features = (const float*)d_in[1];  // (384, 50000)
    const int*   train_labels   = (const int*)d_in[2];    // (256, 50000)
    int*         out            = (int*)d_out;            // (8, 224, 224) int32

    float* ws_vals = (float*)d_ws;                                    // 1600*400 floats
    int*   ws_idx  = (int*)((char*)d_ws + (size_t)WSROWS * CAND * sizeof(float));

    sim_topk_kernel<<<dim3(NTILES, NSPLIT), 256, 0, stream>>>(
        test_feature, train_features, ws_vals, ws_idx);

    vote_kernel<<<NROWS_TOT, 256, 0, stream>>>(
        ws_vals, ws_idx, test_feature, train_features, train_labels, out);
}

// Round 5
// 957.887 us; speedup vs baseline: 7.2243x; 1.2582x over previous
//
#include <hip/hip_runtime.h>
#include <math.h>

#define DIM 384
#define NTRAIN 50000
#define NPAD 50048          // 782 * 64
#define NPATCH 196
#define NROWS_TOT 1568
#define WSROWS 1600         // 25 tiles * 64 rows (rows >=1568 clamped duplicates)
#define K 20
#define NCLS 21
#define MROWS 64
#define NT 128
#define BK 32
#define NSTAGE 12           // 384/32
#define NCHUNKS 391         // ceil(50000/128)
#define NSPLIT 20
#define NTILES 25
#define CAND (NSPLIT * K)   // 400
#define RSEL 32

#define A_STRIDE 40
#define B_STRIDE 40
#define CS_STRIDE 132
#define AS_H_OFF 0
#define AS_L_OFF 5120
#define BS_H_OFF 10240
#define BS_L_OFF 20480
#define CS_OFF   30720
#define SMEM_BYTES 64512

// fast-path workspace layout (bytes)
#define WS_BTH   0ULL
#define WS_BTL   38436864ULL
#define WS_BT32  76873728ULL
#define WS_LAB   153747456ULL
#define WS_AH    166559744ULL
#define WS_AL    167788544ULL
#define WS_CVAL  169017344ULL
#define WS_CIDX  171577344ULL
#define WS_NEED  174137344ULL

typedef __attribute__((ext_vector_type(8))) short bf16x8;
typedef __attribute__((ext_vector_type(4))) float f32x4;

__device__ __forceinline__ unsigned pack2bf(float f0, float f1) {
    return (__float_as_uint(f0) >> 16) | (__float_as_uint(f1) & 0xFFFF0000u);
}

// split 8 fp32 -> bf16 hi plane + exact-residual lo plane (truncation split)
__device__ __forceinline__ void split8(const float* f, uint4& hi, uint4& lo) {
    float r[8];
    #pragma unroll
    for (int j = 0; j < 8; ++j) {
        const unsigned b = __float_as_uint(f[j]) & 0xFFFF0000u;
        r[j] = f[j] - __uint_as_float(b);
    }
    hi.x = pack2bf(f[0], f[1]); hi.y = pack2bf(f[2], f[3]);
    hi.z = pack2bf(f[4], f[5]); hi.w = pack2bf(f[6], f[7]);
    lo.x = pack2bf(r[0], r[1]); lo.y = pack2bf(r[2], r[3]);
    lo.z = pack2bf(r[4], r[5]); lo.w = pack2bf(r[6], r[7]);
}

__device__ __forceinline__ void topk_insert(float (&vals)[K], int (&idxs)[K], float s, int id)
{
    if (s <= vals[K - 1]) return;
    #pragma unroll
    for (int j = K - 1; j >= 1; --j) {
        const bool gt  = s > vals[j];
        const bool gtm = s > vals[j - 1];
        const float nv = gt ? (gtm ? vals[j - 1] : s)  : vals[j];
        const int   ni = gt ? (gtm ? idxs[j - 1] : id) : idxs[j];
        vals[j] = nv;
        idxs[j] = ni;
    }
    const bool gt0 = s > vals[0];
    vals[0] = gt0 ? s  : vals[0];
    idxs[0] = gt0 ? id : idxs[0];
}

// ---------------- prep kernels (fast path) ----------------

// B (384 x 50000 fp32, k-major) -> BtH/BtL (50048 x 384 bf16, n-major) + Bt32 (n-major fp32)
__global__ __launch_bounds__(256) void prep_bt(
    const float* __restrict__ B, short* __restrict__ BtH, short* __restrict__ BtL,
    float* __restrict__ Bt32)
{
    __shared__ float tile[64][65];
    const int n0 = blockIdx.x * 64;
    const int t  = threadIdx.x;
    const int rnl = t & 63, rk0 = t >> 6;       // read mapping
    const int wnl = t >> 2, wpart = t & 3;      // write mapping

    for (int kt = 0; kt < 6; ++kt) {
        #pragma unroll 4
        for (int i = 0; i < 16; ++i) {
            const int kl = rk0 + 4 * i;
            const int n  = n0 + rnl;
            tile[kl][rnl] = (n < NTRAIN) ? B[(size_t)(kt * 64 + kl) * NTRAIN + n] : 0.0f;
        }
        __syncthreads();
        float f[16];
        #pragma unroll
        for (int j = 0; j < 16; ++j) f[j] = tile[wpart * 16 + j][wnl];
        const size_t rowb = (size_t)(n0 + wnl) * DIM + kt * 64 + wpart * 16;
        #pragma unroll
        for (int q = 0; q < 4; ++q)
            *(float4*)(Bt32 + rowb + q * 4) = make_float4(f[q*4], f[q*4+1], f[q*4+2], f[q*4+3]);
        uint4 h0, l0, h1, l1;
        split8(f, h0, l0);
        split8(f + 8, h1, l1);
        *(uint4*)(BtH + rowb)     = h0;
        *(uint4*)(BtH + rowb + 8) = h1;
        *(uint4*)(BtL + rowb)     = l0;
        *(uint4*)(BtL + rowb + 8) = l1;
        __syncthreads();
    }
}

// A (1568 x 384 fp32) -> AH/AL (1600 x 384 bf16), rows >=1568 clamp to 1567
__global__ __launch_bounds__(256) void prep_a(
    const float* __restrict__ A, short* __restrict__ AH, short* __restrict__ AL)
{
    const int gid = blockIdx.x * 256 + threadIdx.x;     // < 1600*48
    const int row = gid / 48;
    const int g   = gid % 48;
    const int src = (row < NROWS_TOT) ? row : (NROWS_TOT - 1);
    float f[8];
    const float4 f0 = *(const float4*)(A + (size_t)src * DIM + g * 8);
    const float4 f1 = *(const float4*)(A + (size_t)src * DIM + g * 8 + 4);
    f[0]=f0.x; f[1]=f0.y; f[2]=f0.z; f[3]=f0.w;
    f[4]=f1.x; f[5]=f1.y; f[6]=f1.z; f[7]=f1.w;
    uint4 hi, lo;
    split8(f, hi, lo);
    *(uint4*)(AH + (size_t)row * DIM + g * 8) = hi;
    *(uint4*)(AL + (size_t)row * DIM + g * 8) = lo;
}

// labels (256 x 50000 int32) -> labT8 (50048 x 256 int8)
__global__ __launch_bounds__(256) void prep_lab(
    const int* __restrict__ labels, signed char* __restrict__ labT8)
{
    __shared__ char lt[64][260];
    const int n0 = blockIdx.x * 64;
    const int t  = threadIdx.x;
    const int rc = t & 63, rr0 = t >> 6;
    #pragma unroll 4
    for (int i = 0; i < 64; ++i) {
        const int r = rr0 + 4 * i;
        const int n = n0 + rc;
        lt[rc][r] = (char)((n < NTRAIN) ? labels[(size_t)r * NTRAIN + n] : 0);
    }
    __syncthreads();
    const int wnl = t >> 2, wpart = t & 3;
    const unsigned* src = (const unsigned*)&lt[wnl][wpart * 64];
    uint4* dst = (uint4*)(labT8 + (size_t)(n0 + wnl) * 256 + wpart * 64);
    #pragma unroll
    for (int q = 0; q < 4; ++q)
        dst[q] = make_uint4(src[q*4], src[q*4+1], src[q*4+2], src[q*4+3]);
}

// ---------------- fast sim kernel ----------------

__global__ __launch_bounds__(256, 2) void sim_topk_fast(
    const short* __restrict__ AH, const short* __restrict__ AL,
    const short* __restrict__ BtH, const short* __restrict__ BtL,
    float* __restrict__ out_vals, int* __restrict__ out_idx)
{
    __shared__ __align__(16) char smem[SMEM_BYTES];
    short* as_h = (short*)(smem + AS_H_OFF);
    short* as_l = (short*)(smem + AS_L_OFF);
    short* bs_h = (short*)(smem + BS_H_OFF);
    short* bs_l = (short*)(smem + BS_L_OFF);
    float* Cs   = (float*)(smem + CS_OFF);

    const int t  = threadIdx.x;
    const int r0 = blockIdx.x * MROWS;
    const int sp = blockIdx.y;
    const int w  = t >> 6;
    const int l  = t & 63;
    const int wn = w * 32;
    const int lm = l & 15;
    const int lq = l >> 4;

    const int a_row  = t >> 2;
    const int a_dg   = (t & 3) * 8;
    const int b_n    = t >> 1;
    const int b_half = t & 1;
    const int s_row  = t >> 2;
    const int s_seg  = t & 3;

    const int nch = (NCHUNKS - sp + NSPLIT - 1) / NSPLIT;

    float vals[K]; int idxs[K];
    #pragma unroll
    for (int k = 0; k < K; ++k) { vals[k] = -INFINITY; idxs[k] = -1; }

    uint4 pah, pal, pbh0, pbh1, pbl0, pbl1;

    auto prefetch = [&](int ci, int ks) {
        if (ci >= nch) return;
        const int kb = ks * BK;
        const size_t ab = (size_t)(r0 + a_row) * DIM + kb + a_dg;
        pah = *(const uint4*)(AH + ab);
        pal = *(const uint4*)(AL + ab);
        const int n = (sp + NSPLIT * ci) * NT + b_n;     // < 50048, rows padded with zeros
        const size_t bb = (size_t)n * DIM + kb + b_half * 16;
        pbh0 = *(const uint4*)(BtH + bb);
        pbh1 = *(const uint4*)(BtH + bb + 8);
        pbl0 = *(const uint4*)(BtL + bb);
        pbl1 = *(const uint4*)(BtL + bb + 8);
    };

    auto commit = [&]() {
        *(uint4*)(as_h + a_row * A_STRIDE + a_dg) = pah;
        *(uint4*)(as_l + a_row * A_STRIDE + a_dg) = pal;
        const int bo = b_n * B_STRIDE + b_half * 16;
        *(uint4*)(bs_h + bo)     = pbh0;
        *(uint4*)(bs_h + bo + 8) = pbh1;
        *(uint4*)(bs_l + bo)     = pbl0;
        *(uint4*)(bs_l + bo + 8) = pbl1;
    };

    prefetch(0, 0);

    for (int ci = 0; ci < nch; ++ci) {
        const int ch = sp + NSPLIT * ci;
        f32x4 acc[4][2];
        #pragma unroll
        for (int im = 0; im < 4; ++im)
            #pragma unroll
            for (int in_ = 0; in_ < 2; ++in_)
                acc[im][in_] = (f32x4){0.f, 0.f, 0.f, 0.f};

        for (int ks = 0; ks < NSTAGE; ++ks) {
            __syncthreads();
            commit();
            __syncthreads();
            int nks = ks + 1, nci = ci;
            if (nks == NSTAGE) { nks = 0; nci = ci + 1; }
            prefetch(nci, nks);

            bf16x8 af[4][2], bf[2][2];
            #pragma unroll
            for (int im = 0; im < 4; ++im) {
                const int ao = (im * 16 + lm) * A_STRIDE + lq * 8;
                af[im][0] = *(const bf16x8*)(as_h + ao);
                af[im][1] = *(const bf16x8*)(as_l + ao);
            }
            #pragma unroll
            for (int in_ = 0; in_ < 2; ++in_) {
                const int nloc = wn + in_ * 16 + lm;
                const int bo = nloc * B_STRIDE + lq * 8;
                bf[in_][0] = *(const bf16x8*)(bs_h + bo);
                bf[in_][1] = *(const bf16x8*)(bs_l + bo);
            }
            #pragma unroll
            for (int im = 0; im < 4; ++im) {
                #pragma unroll
                for (int in_ = 0; in_ < 2; ++in_) {
                    acc[im][in_] = __builtin_amdgcn_mfma_f32_16x16x32_bf16(af[im][0], bf[in_][0], acc[im][in_], 0, 0, 0);
                    acc[im][in_] = __builtin_amdgcn_mfma_f32_16x16x32_bf16(af[im][0], bf[in_][1], acc[im][in_], 0, 0, 0);
                    acc[im][in_] = __builtin_amdgcn_mfma_f32_16x16x32_bf16(af[im][1], bf[in_][0], acc[im][in_], 0, 0, 0);
                }
            }
        }

        #pragma unroll
        for (int im = 0; im < 4; ++im)
            #pragma unroll
            for (int in_ = 0; in_ < 2; ++in_)
                #pragma unroll
                for (int r = 0; r < 4; ++r)
                    Cs[(im * 16 + lq * 4 + r) * CS_STRIDE + wn + in_ * 16 + lm] = acc[im][in_][r];
        __syncthreads();

        const int n0 = ch * NT;
        #pragma unroll
        for (int i = 0; i < 32; ++i) {
            const int coff = s_seg + 4 * i;
            const int col  = n0 + coff;
            const float s  = Cs[s_row * CS_STRIDE + coff];
            if (col < NTRAIN) topk_insert(vals, idxs, s, col);
        }
    }

    const int gr = r0 + s_row;
    for (int round = 0; round < K; ++round) {
        float hv = vals[0]; int hi = idxs[0]; int hl = s_seg;
        #pragma unroll
        for (int off = 2; off >= 1; off >>= 1) {
            const float ov = __shfl_xor(hv, off, 4);
            const int   oi = __shfl_xor(hi, off, 4);
            const int   ol = __shfl_xor(hl, off, 4);
            if (ov > hv || (ov == hv && (unsigned)oi < (unsigned)hi)) { hv = ov; hi = oi; hl = ol; }
        }
        const bool won = (hl == s_seg);
        #pragma unroll
        for (int j = 0; j < K - 1; ++j) {
            vals[j] = won ? vals[j + 1] : vals[j];
            idxs[j] = won ? idxs[j + 1] : idxs[j];
        }
        if (won) vals[K - 1] = -INFINITY;
        if (s_seg == 0) {
            const int o = (gr * NSPLIT + sp) * K + round;
            out_vals[o] = hv;
            out_idx[o]  = hi;
        }
    }
}

// ---------------- fast vote kernel ----------------

__global__ __launch_bounds__(256) void vote_fast(
    const float* __restrict__ cvals,
    const int*   __restrict__ cidx,
    const float* __restrict__ A,
    const float* __restrict__ Bt32,        // (50048, 384) n-major
    const signed char* __restrict__ labT8, // (50048, 256) n-major
    int*         __restrict__ out)
{
    __shared__ float  sv[CAND];
    __shared__ int    si[CAND];
    __shared__ float  Arow[DIM];
    __shared__ int    sel_i[RSEL];
    __shared__ double cpart[RSEL][8];
    __shared__ double dv[RSEL];
    __shared__ double tvd[K];
    __shared__ int    ti[K];
    __shared__ double wgt[K];

    const int gr = blockIdx.x;
    const int t  = threadIdx.x;

    for (int i = t; i < DIM; i += 256) Arow[i] = A[(size_t)gr * DIM + i];
    for (int e = t; e < CAND; e += 256) {
        sv[e] = cvals[gr * CAND + e];
        si[e] = cidx[gr * CAND + e];
    }
    __syncthreads();

    for (int e = t; e < CAND; e += 256) {
        const float v = sv[e];
        const unsigned id = (unsigned)si[e];
        int rank = 0;
        for (int j = 0; j < CAND; ++j) {
            const float vj = sv[j];
            const unsigned ij = (unsigned)si[j];
            if (vj > v || (vj == v && ij < id)) rank++;
        }
        if (rank < RSEL) sel_i[rank] = (int)id;
    }
    __syncthreads();

    {
        const int cand = t >> 3;
        const int part = t & 7;
        const int idx  = sel_i[cand];
        const int d0   = part * (DIM / 8);
        const float* brow = Bt32 + (size_t)idx * DIM + d0;
        double acc = 0.0;
        #pragma unroll
        for (int q = 0; q < 12; ++q) {
            const float4 b4 = *(const float4*)(brow + q * 4);
            acc = fma((double)Arow[d0 + q*4 + 0], (double)b4.x, acc);
            acc = fma((double)Arow[d0 + q*4 + 1], (double)b4.y, acc);
            acc = fma((double)Arow[d0 + q*4 + 2], (double)b4.z, acc);
            acc = fma((double)Arow[d0 + q*4 + 3], (double)b4.w, acc);
        }
        cpart[cand][part] = acc;
    }
    __syncthreads();

    if (t < RSEL) {
        double s = 0.0;
        #pragma unroll
        for (int p = 0; p < 8; ++p) s += cpart[t][p];
        dv[t] = s;
    }
    __syncthreads();

    if (t < RSEL) {
        const double v = dv[t];
        const unsigned id = (unsigned)sel_i[t];
        int rank = 0;
        for (int j = 0; j < RSEL; ++j) {
            const double vj = dv[j];
            const unsigned ij = (unsigned)sel_i[j];
            if (vj > v || (vj == v && ij < id)) rank++;
        }
        if (rank < K) { tvd[rank] = v; ti[rank] = (int)id; }
    }
    __syncthreads();

    if (t == 0) {
        const double m = tvd[0];
        double e[K];
        double s = 0.0;
        #pragma unroll
        for (int k = 0; k < K; ++k) { e[k] = exp(tvd[k] - m); s += e[k]; }
        const double inv = 1.0 / s;
        #pragma unroll
        for (int k = 0; k < K; ++k) wgt[k] = e[k] * inv;
    }
    __syncthreads();

    int lbl[K];
    #pragma unroll
    for (int k = 0; k < K; ++k) lbl[k] = (int)labT8[(size_t)ti[k] * 256 + t];

    double v[NCLS];
    #pragma unroll
    for (int c = 0; c < NCLS; ++c) v[c] = 0.0;
    #pragma unroll
    for (int k = 0; k < K; ++k) {
        const double wk = wgt[k];
        const int    lk = lbl[k];
        #pragma unroll
        for (int c = 0; c < NCLS; ++c) v[c] += (lk == c) ? wk : 0.0;
    }

    double best = v[0];
    int bi = 0;
    #pragma unroll
    for (int c = 1; c < NCLS; ++c) {
        if (v[c] > best) { best = v[c]; bi = c; }
    }

    const int b  = gr / NPATCH;
    const int p  = gr % NPATCH;
    const int pr = p / 14, pc = p % 14;
    const int i  = t >> 4, j = t & 15;
    out[b * (224 * 224) + (pr * 16 + i) * 224 + (pc * 16 + j)] = bi;
}

// ---------------- fallback (R4) kernels ----------------

__global__ __launch_bounds__(256, 2) void sim_topk_fb(
    const float* __restrict__ A, const float* __restrict__ B,
    float* __restrict__ out_vals, int* __restrict__ out_idx)
{
    __shared__ __align__(16) char smem[SMEM_BYTES];
    short* as_h = (short*)(smem + AS_H_OFF);
    short* as_l = (short*)(smem + AS_L_OFF);
    short* bs_h = (short*)(smem + BS_H_OFF);
    short* bs_l = (short*)(smem + BS_L_OFF);
    float* Cs   = (float*)(smem + CS_OFF);

    const int t  = threadIdx.x;
    const int r0 = blockIdx.x * MROWS;
    const int sp = blockIdx.y;
    const int w  = t >> 6;
    const int l  = t & 63;
    const int wn = w * 32;
    const int lm = l & 15;
    const int lq = l >> 4;

    const int a_row = t >> 2;
    const int a_dg  = (t & 3) * 8;
    const int a_r   = (r0 + a_row < NROWS_TOT) ? (r0 + a_row) : (NROWS_TOT - 1);
    const int b_n   = t & 127;
    const int b_ks0 = t >> 7;
    const int b_sw  = ((b_n >> 3) & 3) * 8;
    const int s_row = t >> 2;
    const int s_seg = t & 3;

    const int nch = (NCHUNKS - sp + NSPLIT - 1) / NSPLIT;

    float vals[K]; int idxs[K];
    #pragma unroll
    for (int k = 0; k < K; ++k) { vals[k] = -INFINITY; idxs[k] = -1; }

    float pa[8];
    float pb[2][8];

    auto prefetch = [&](int ci, int ks) {
        if (ci >= nch) return;
        const int kb = ks * BK;
        const float* ap = A + (size_t)a_r * DIM + kb + a_dg;
        const float4 t0 = *(const float4*)(ap);
        const float4 t1 = *(const float4*)(ap + 4);
        pa[0]=t0.x; pa[1]=t0.y; pa[2]=t0.z; pa[3]=t0.w;
        pa[4]=t1.x; pa[5]=t1.y; pa[6]=t1.z; pa[7]=t1.w;
        const int n = (sp + NSPLIT * ci) * NT + b_n;
        const bool v = (n < NTRAIN);
        #pragma unroll
        for (int u = 0; u < 2; ++u) {
            const int kr = kb + (b_ks0 + 2*u) * 8;
            #pragma unroll
            for (int j = 0; j < 8; ++j)
                pb[u][j] = v ? B[(size_t)(kr + j) * NTRAIN + n] : 0.0f;
        }
    };

    auto commit = [&]() {
        uint4 hi, lo;
        split8(pa, hi, lo);
        *(uint4*)(as_h + a_row * A_STRIDE + a_dg) = hi;
        *(uint4*)(as_l + a_row * A_STRIDE + a_dg) = lo;
        #pragma unroll
        for (int u = 0; u < 2; ++u) {
            split8(pb[u], hi, lo);
            const int koff = (((b_ks0 + 2*u) * 8) ^ b_sw);
            *(uint4*)(bs_h + b_n * B_STRIDE + koff) = hi;
            *(uint4*)(bs_l + b_n * B_STRIDE + koff) = lo;
        }
    };

    prefetch(0, 0);

    for (int ci = 0; ci < nch; ++ci) {
        const int ch = sp + NSPLIT * ci;
        f32x4 acc[4][2];
        #pragma unroll
        for (int im = 0; im < 4; ++im)
            #pragma unroll
            for (int in_ = 0; in_ < 2; ++in_)
                acc[im][in_] = (f32x4){0.f, 0.f, 0.f, 0.f};

        for (int ks = 0; ks < NSTAGE; ++ks) {
            __syncthreads();
            commit();
            __syncthreads();
            int nks = ks + 1, nci = ci;
            if (nks == NSTAGE) { nks = 0; nci = ci + 1; }
            prefetch(nci, nks);

            bf16x8 af[4][2], bf[2][2];
            #pragma unroll
            for (int im = 0; im < 4; ++im) {
                const int ao = (im * 16 + lm) * A_STRIDE + lq * 8;
                af[im][0] = *(const bf16x8*)(as_h + ao);
                af[im][1] = *(const bf16x8*)(as_l + ao);
            }
            #pragma unroll
            for (int in_ = 0; in_ < 2; ++in_) {
                const int nloc = wn + in_ * 16 + lm;
                const int bo = nloc * B_STRIDE + ((lq * 8) ^ (((nloc >> 3) & 3) * 8));
                bf[in_][0] = *(const bf16x8*)(bs_h + bo);
                bf[in_][1] = *(const bf16x8*)(bs_l + bo);
            }
            #pragma unroll
            for (int im = 0; im < 4; ++im) {
                #pragma unroll
                for (int in_ = 0; in_ < 2; ++in_) {
                    acc[im][in_] = __builtin_amdgcn_mfma_f32_16x16x32_bf16(af[im][0], bf[in_][0], acc[im][in_], 0, 0, 0);
                    acc[im][in_] = __builtin_amdgcn_mfma_f32_16x16x32_bf16(af[im][0], bf[in_][1], acc[im][in_], 0, 0, 0);
                    acc[im][in_] = __builtin_amdgcn_mfma_f32_16x16x32_bf16(af[im][1], bf[in_][0], acc[im][in_], 0, 0, 0);
                }
            }
        }

        #pragma unroll
        for (int im = 0; im < 4; ++im)
            #pragma unroll
            for (int in_ = 0; in_ < 2; ++in_)
                #pragma unroll
                for (int r = 0; r < 4; ++r)
                    Cs[(im * 16 + lq * 4 + r) * CS_STRIDE + wn + in_ * 16 + lm] = acc[im][in_][r];
        __syncthreads();

        const int n0 = ch * NT;
        #pragma unroll
        for (int i = 0; i < 32; ++i) {
            const int coff = s_seg + 4 * i;
            const int col  = n0 + coff;
            const float s  = Cs[s_row * CS_STRIDE + coff];
            if (col < NTRAIN) topk_insert(vals, idxs, s, col);
        }
    }

    const int gr = r0 + s_row;
    for (int round = 0; round < K; ++round) {
        float hv = vals[0]; int hi = idxs[0]; int hl = s_seg;
        #pragma unroll
        for (int off = 2; off >= 1; off >>= 1) {
            const float ov = __shfl_xor(hv, off, 4);
            const int   oi = __shfl_xor(hi, off, 4);
            const int   ol = __shfl_xor(hl, off, 4);
            if (ov > hv || (ov == hv && (unsigned)oi < (unsigned)hi)) { hv = ov; hi = oi; hl = ol; }
        }
        const bool won = (hl == s_seg);
        #pragma unroll
        for (int j = 0; j < K - 1; ++j) {
            vals[j] = won ? vals[j + 1] : vals[j];
            idxs[j] = won ? idxs[j + 1] : idxs[j];
        }
        if (won) vals[K - 1] = -INFINITY;
        if (s_seg == 0) {
            const int o = (gr * NSPLIT + sp) * K + round;
            out_vals[o] = hv;
            out_idx[o]  = hi;
        }
    }
}

__global__ __launch_bounds__(256) void vote_fb(
    const float* __restrict__ cvals,
    const int*   __restrict__ cidx,
    const float* __restrict__ A,
    const float* __restrict__ B,
    const int*   __restrict__ labels,
    int*         __restrict__ out)
{
    __shared__ float  sv[CAND];
    __shared__ int    si[CAND];
    __shared__ float  Arow[DIM];
    __shared__ int    sel_i[RSEL];
    __shared__ double cpart[RSEL][8];
    __shared__ double dv[RSEL];
    __shared__ double tvd[K];
    __shared__ int    ti[K];
    __shared__ double wgt[K];

    const int gr = blockIdx.x;
    const int t  = threadIdx.x;

    for (int i = t; i < DIM; i += 256) Arow[i] = A[(size_t)gr * DIM + i];
    for (int e = t; e < CAND; e += 256) {
        sv[e] = cvals[gr * CAND + e];
        si[e] = cidx[gr * CAND + e];
    }
    __syncthreads();

    for (int e = t; e < CAND; e += 256) {
        const float v = sv[e];
        const unsigned id = (unsigned)si[e];
        int rank = 0;
        for (int j = 0; j < CAND; ++j) {
            const float vj = sv[j];
            const unsigned ij = (unsigned)si[j];
            if (vj > v || (vj == v && ij < id)) rank++;
        }
        if (rank < RSEL) sel_i[rank] = (int)id;
    }
    __syncthreads();

    {
        const int cand = t >> 3;
        const int part = t & 7;
        const int idx  = sel_i[cand];
        const int d0   = part * (DIM / 8);
        double acc = 0.0;
        #pragma unroll 8
        for (int d = d0; d < d0 + DIM / 8; ++d) {
            acc = fma((double)Arow[d], (double)B[(size_t)d * NTRAIN + idx], acc);
        }
        cpart[cand][part] = acc;
    }
    __syncthreads();

    if (t < RSEL) {
        double s = 0.0;
        #pragma unroll
        for (int p = 0; p < 8; ++p) s += cpart[t][p];
        dv[t] = s;
    }
    __syncthreads();

    if (t < RSEL) {
        const double v = dv[t];
        const unsigned id = (unsigned)sel_i[t];
        int rank = 0;
        for (int j = 0; j < RSEL; ++j) {
            const double vj = dv[j];
            const unsigned ij = (unsigned)sel_i[j];
            if (vj > v || (vj == v && ij < id)) rank++;
        }
        if (rank < K) { tvd[rank] = v; ti[rank] = (int)id; }
    }
    __syncthreads();

    if (t == 0) {
        const double m = tvd[0];
        double e[K];
        double s = 0.0;
        #pragma unroll
        for (int k = 0; k < K; ++k) { e[k] = exp(tvd[k] - m); s += e[k]; }
        const double inv = 1.0 / s;
        #pragma unroll
        for (int k = 0; k < K; ++k) wgt[k] = e[k] * inv;
    }
    __syncthreads();

    int lbl[K];
    #pragma unroll
    for (int k = 0; k < K; ++k) lbl[k] = labels[(size_t)t * NTRAIN + ti[k]];

    double v[NCLS];
    #pragma unroll
    for (int c = 0; c < NCLS; ++c) v[c] = 0.0;
    #pragma unroll
    for (int k = 0; k < K; ++k) {
        const double wk = wgt[k];
        const int    lk = lbl[k];
        #pragma unroll
        for (int c = 0; c < NCLS; ++c) v[c] += (lk == c) ? wk : 0.0;
    }

    double best = v[0];
    int bi = 0;
    #pragma unroll
    for (int c = 1; c < NCLS; ++c) {
        if (v[c] > best) { best = v[c]; bi = c; }
    }

    const int b  = gr / NPATCH;
    const int p  = gr % NPATCH;
    const int pr = p / 14, pc = p % 14;
    const int i  = t >> 4, j = t & 15;
    out[b * (224 * 224) + (pr * 16 + i) * 224 + (pc * 16 + j)] = bi;
}

extern "C" void kernel_launch(void* const* d_in, const int* in_sizes, int n_in,
                              void* d_out, int out_size, void* d_ws, size_t ws_size,
                              hipStream_t stream)
{
    const float* test_feature   = (const float*)d_in[0];
    const float* train_features = (const float*)d_in[1];
    const int*   train_labels   = (const int*)d_in[2];
    int*         out            = (int*)d_out;

    if (ws_size >= WS_NEED) {
        char* w = (char*)d_ws;
        short*       BtH   = (short*)(w + WS_BTH);
        short*       BtL   = (short*)(w + WS_BTL);
        float*       Bt32  = (float*)(w + WS_BT32);
        signed char* labT8 = (signed char*)(w + WS_LAB);
        short*       AH    = (short*)(w + WS_AH);
        short*       AL    = (short*)(w + WS_AL);
        float*       cval  = (float*)(w + WS_CVAL);
        int*         cidx  = (int*)(w + WS_CIDX);

        prep_bt<<<NPAD / 64, 256, 0, stream>>>(train_features, BtH, BtL, Bt32);
        prep_a<<<WSROWS * 48 / 256, 256, 0, stream>>>(test_feature, AH, AL);
        prep_lab<<<NPAD / 64, 256, 0, stream>>>(train_labels, labT8);
        sim_topk_fast<<<dim3(NTILES, NSPLIT), 256, 0, stream>>>(AH, AL, BtH, BtL, cval, cidx);
        vote_fast<<<NROWS_TOT, 256, 0, stream>>>(cval, cidx, test_feature, Bt32, labT8, out);
    } else {
        float* cval = (float*)d_ws;
        int*   cidx = (int*)((char*)d_ws + (size_t)WSROWS * CAND * sizeof(float));
        sim_topk_fb<<<dim3(NTILES, NSPLIT), 256, 0, stream>>>(test_feature, train_features, cval, cidx);
        vote_fb<<<NROWS_TOT, 256, 0, stream>>>(cval, cidx, test_feature, train_features, train_labels, out);
    }
}

// Round 6
// 671.241 us; speedup vs baseline: 10.3093x; 1.4270x over previous
//
#include <hip/hip_runtime.h>
#include <math.h>

#define DIM 384
#define NTRAIN 50000
#define NPAD 50048          // 782*64 = 3128*16
#define NPATCH 196
#define NROWS_TOT 1568
#define WSROWS 1600         // 25 tiles * 64 rows
#define K 20
#define NCLS 21
#define MROWS 64
#define NT 128
#define NSTAGE 12           // 384/32
#define NCHUNKS 391         // ceil(50000/128)
#define NSPLIT 20
#define NTILES 25
#define CAND (NSPLIT * K)   // 400
#define RSEL 32

// workspace layout (bytes)
#define WS_BTH   0ULL                 // frag-layout bf16 B^T: [nb 3128][kg 48][nloc 16][8]  = 38,436,864
#define WS_BT32  38436864ULL          // n-major fp32 B^T: [50048][384]                      = 76,873,728
#define WS_LAB   115310592ULL         // labels transposed int8: [50048][256]                = 12,812,288
#define WS_AH    128122880ULL         // frag-layout bf16 A: [tile 25][kg 48][mloc 64][8]    = 1,228,800
#define WS_CVAL  129351680ULL         // 1600*400 f32
#define WS_CIDX  131911680ULL         // 1600*400 i32
#define WS_NEED  134471680ULL

typedef __attribute__((ext_vector_type(8))) short bf16x8;
typedef __attribute__((ext_vector_type(4))) float f32x4;

__device__ __forceinline__ unsigned bf16rne(float f) {
    const unsigned u = __float_as_uint(f);
    return (u + 0x7FFFu + ((u >> 16) & 1u)) >> 16;      // round-nearest-even
}
__device__ __forceinline__ uint4 pack8r(const float* f) {
    uint4 o;
    o.x = bf16rne(f[0]) | (bf16rne(f[1]) << 16);
    o.y = bf16rne(f[2]) | (bf16rne(f[3]) << 16);
    o.z = bf16rne(f[4]) | (bf16rne(f[5]) << 16);
    o.w = bf16rne(f[6]) | (bf16rne(f[7]) << 16);
    return o;
}

// Branchless sorted-descending top-K insertion (static indices -> VGPRs).
__device__ __forceinline__ void topk_insert(float (&vals)[K], int (&idxs)[K], float s, int id)
{
    if (s <= vals[K - 1]) return;   // ties keep earlier (lower col) -> matches lax.top_k
    #pragma unroll
    for (int j = K - 1; j >= 1; --j) {
        const bool gt  = s > vals[j];
        const bool gtm = s > vals[j - 1];
        const float nv = gt ? (gtm ? vals[j - 1] : s)  : vals[j];
        const int   ni = gt ? (gtm ? idxs[j - 1] : id) : idxs[j];
        vals[j] = nv;
        idxs[j] = ni;
    }
    const bool gt0 = s > vals[0];
    vals[0] = gt0 ? s  : vals[0];
    idxs[0] = gt0 ? id : idxs[0];
}

// ---------------- prep kernels ----------------

// B (384 x 50000 fp32, k-major) -> BtH frag layout [nb][kg][nloc][8] bf16 + Bt32 (n-major fp32)
__global__ __launch_bounds__(256) void prep_bt(
    const float* __restrict__ B, uint4* __restrict__ BtH4, float* __restrict__ Bt32)
{
    __shared__ float tile[64][65];
    const int n0 = blockIdx.x * 64;
    const int t  = threadIdx.x;
    const int rnl = t & 63, rk0 = t >> 6;
    const int wnl = t >> 2, wpart = t & 3;

    for (int kt = 0; kt < 6; ++kt) {
        #pragma unroll 4
        for (int i = 0; i < 16; ++i) {
            const int kl = rk0 + 4 * i;
            const int n  = n0 + rnl;
            tile[kl][rnl] = (n < NTRAIN) ? B[(size_t)(kt * 64 + kl) * NTRAIN + n] : 0.0f;
        }
        __syncthreads();
        float f[16];
        #pragma unroll
        for (int j = 0; j < 16; ++j) f[j] = tile[wpart * 16 + j][wnl];
        const int n = n0 + wnl;
        const size_t rowb = (size_t)n * DIM + kt * 64 + wpart * 16;
        #pragma unroll
        for (int q = 0; q < 4; ++q)
            *(float4*)(Bt32 + rowb + q * 4) = make_float4(f[q*4], f[q*4+1], f[q*4+2], f[q*4+3]);
        const int nb = n >> 4, nloc = n & 15;
        const int kg0 = kt * 8 + wpart * 2;
        BtH4[((size_t)nb * 48 + kg0)     * 16 + nloc] = pack8r(f);
        BtH4[((size_t)nb * 48 + kg0 + 1) * 16 + nloc] = pack8r(f + 8);
        __syncthreads();
    }
}

// A (1568 x 384 fp32) -> AH frag layout [tile][kg][mloc][8] bf16 (rows clamp to 1567)
__global__ __launch_bounds__(256) void prep_a(
    const float* __restrict__ A, uint4* __restrict__ AH4)
{
    const int gid  = blockIdx.x * 256 + threadIdx.x;    // < 25*48*64 = 76800
    const int tile = gid / 3072;
    const int rem  = gid % 3072;
    const int kg   = rem >> 6;
    const int mloc = rem & 63;
    const int row  = tile * 64 + mloc;
    const int src  = (row < NROWS_TOT) ? row : (NROWS_TOT - 1);
    float f[8];
    const float4 f0 = *(const float4*)(A + (size_t)src * DIM + kg * 8);
    const float4 f1 = *(const float4*)(A + (size_t)src * DIM + kg * 8 + 4);
    f[0]=f0.x; f[1]=f0.y; f[2]=f0.z; f[3]=f0.w;
    f[4]=f1.x; f[5]=f1.y; f[6]=f1.z; f[7]=f1.w;
    AH4[((size_t)tile * 48 + kg) * 64 + mloc] = pack8r(f);
}

// labels (256 x 50000 int32) -> labT8 (50048 x 256 int8)
__global__ __launch_bounds__(256) void prep_lab(
    const int* __restrict__ labels, signed char* __restrict__ labT8)
{
    __shared__ char lt[64][260];
    const int n0 = blockIdx.x * 64;
    const int t  = threadIdx.x;
    const int rc = t & 63, rr0 = t >> 6;
    #pragma unroll 4
    for (int i = 0; i < 64; ++i) {
        const int r = rr0 + 4 * i;
        const int n = n0 + rc;
        lt[rc][r] = (char)((n < NTRAIN) ? labels[(size_t)r * NTRAIN + n] : 0);
    }
    __syncthreads();
    const int wnl = t >> 2, wpart = t & 3;
    const unsigned* src = (const unsigned*)&lt[wnl][wpart * 64];
    uint4* dst = (uint4*)(labT8 + (size_t)(n0 + wnl) * 256 + wpart * 64);
    #pragma unroll
    for (int q = 0; q < 4; ++q)
        dst[q] = make_uint4(src[q*4], src[q*4+1], src[q*4+2], src[q*4+3]);
}

// ---------------- sim kernel: barrier-free K-loop, register top-k ----------------
// Operand swap: mfma(bf, af, acc) -> lane holds m = l&15 (fixed row), n = lq*4+r.
// Wave grid 2x2: wm = w>>1 (m-half of 32), wn2 = w&1 (n-half of 64).
// A tile (64x384 bf16, frag-interleaved) lives in LDS for the whole block.
__global__ __launch_bounds__(256, 2) void sim_topk_v6(
    const uint4* __restrict__ AH4, const bf16x8* __restrict__ Bt8,
    float* __restrict__ out_vals, int* __restrict__ out_idx)
{
    __shared__ __align__(16) char smem[49152];
    uint4* As4 = (uint4*)smem;
    const bf16x8* As8 = (const bf16x8*)smem;

    const int t    = threadIdx.x;
    const int sp   = blockIdx.x;            // split 0..19 (fast-varying -> XCD affinity)
    const int tile = blockIdx.y;            // 0..24
    const int r0   = tile * MROWS;
    const int w    = t >> 6, l = t & 63;
    const int wm   = w >> 1, wn2 = w & 1;
    const int lm   = l & 15, lq = l >> 4;
    const int lane_c = lq * 16 + lm;

    // stage A once (48 KB, coalesced), then no barriers until the merge
    #pragma unroll
    for (int i = 0; i < 12; ++i) As4[t + 256 * i] = AH4[(size_t)tile * 3072 + t + 256 * i];
    __syncthreads();

    const int nch = (NCHUNKS - sp + NSPLIT - 1) / NSPLIT;

    float vals[2][K]; int idxs[2][K];
    #pragma unroll
    for (int im = 0; im < 2; ++im)
        #pragma unroll
        for (int k = 0; k < K; ++k) { vals[im][k] = -INFINITY; idxs[im][k] = -1; }

    f32x4 acc[2][4];
    bf16x8 bfA[4], bfB[4];

    auto loadB = [&](bf16x8 (&bf)[4], int ch, int ks) {
        const int base = (ch * 8 + wn2 * 4) * 768 + ks * 64 + lane_c;
        #pragma unroll
        for (int in_ = 0; in_ < 4; ++in_) bf[in_] = Bt8[base + in_ * 768];
    };
    auto doStage = [&](bf16x8 (&bf)[4], int ks) {
        #pragma unroll
        for (int im = 0; im < 2; ++im) {
            const bf16x8 af = As8[(ks * 4 + lq) * 64 + wm * 32 + im * 16 + lm];
            #pragma unroll
            for (int in_ = 0; in_ < 4; ++in_)
                acc[im][in_] = __builtin_amdgcn_mfma_f32_16x16x32_bf16(bf[in_], af, acc[im][in_], 0, 0, 0);
        }
    };

    int ch = sp;
    loadB(bfA, ch, 0);

    for (int ci = 0; ci < nch; ++ci) {
        #pragma unroll
        for (int im = 0; im < 2; ++im)
            #pragma unroll
            for (int in_ = 0; in_ < 4; ++in_)
                acc[im][in_] = (f32x4){0.f, 0.f, 0.f, 0.f};

        const int ch_next = (ci + 1 < nch) ? (ch + NSPLIT) : ch;   // clamped (redundant load ok)

        #pragma unroll
        for (int ks2 = 0; ks2 < 6; ++ks2) {
            const int ks = ks2 * 2;
            loadB(bfB, ch, ks + 1);
            doStage(bfA, ks);
            if (ks + 2 < NSTAGE) loadB(bfA, ch, ks + 2);
            else                 loadB(bfA, ch_next, 0);
            doStage(bfB, ks + 1);
        }

        // register top-k scan of this chunk
        const int nbase = ch * NT + wn2 * 64;
        #pragma unroll
        for (int im = 0; im < 2; ++im)
            #pragma unroll
            for (int in_ = 0; in_ < 4; ++in_)
                #pragma unroll
                for (int r = 0; r < 4; ++r) {
                    const int n = nbase + in_ * 16 + lq * 4 + r;
                    if (n < NTRAIN) topk_insert(vals[im], idxs[im], acc[im][in_][r], n);
                }
        ch += NSPLIT;
    }

    // ---- merge: in-wave lq tournament, then cross-wave 2-list merge via LDS ----
    __syncthreads();                       // done reading As8; alias smem
    float* mvv = (float*)smem;             // [64 rows][2 wn2][K]
    int*   mii = (int*)(smem + 64 * 2 * K * 4);

    #pragma unroll
    for (int im = 0; im < 2; ++im) {
        for (int round = 0; round < K; ++round) {
            float hv = vals[im][0]; int hi = idxs[im][0]; int hq = lq;
            {
                float ov = __shfl_xor(hv, 16, 64);
                int   oi = __shfl_xor(hi, 16, 64);
                int   oq = __shfl_xor(hq, 16, 64);
                if (ov > hv || (ov == hv && (unsigned)oi < (unsigned)hi)) { hv = ov; hi = oi; hq = oq; }
                ov = __shfl_xor(hv, 32, 64);
                oi = __shfl_xor(hi, 32, 64);
                oq = __shfl_xor(hq, 32, 64);
                if (ov > hv || (ov == hv && (unsigned)oi < (unsigned)hi)) { hv = ov; hi = oi; hq = oq; }
            }
            const bool won = (hq == lq);
            #pragma unroll
            for (int j = 0; j < K - 1; ++j) {
                vals[im][j] = won ? vals[im][j + 1] : vals[im][j];
                idxs[im][j] = won ? idxs[im][j + 1] : idxs[im][j];
            }
            if (won) vals[im][K - 1] = -INFINITY;
            if (lq == 0) {
                const int row = wm * 32 + im * 16 + lm;
                mvv[(row * 2 + wn2) * K + round] = hv;
                mii[(row * 2 + wn2) * K + round] = hi;
            }
        }
    }
    __syncthreads();

    if (t < MROWS) {
        const float* L0 = &mvv[(t * 2 + 0) * K];
        const float* L1 = &mvv[(t * 2 + 1) * K];
        const int*   I0 = &mii[(t * 2 + 0) * K];
        const int*   I1 = &mii[(t * 2 + 1) * K];
        int p0 = 0, p1 = 0;
        const int obase = ((r0 + t) * NSPLIT + sp) * K;
        for (int round = 0; round < K; ++round) {
            const float v0 = L0[p0], v1 = L1[p1];
            const int   i0 = I0[p0], i1 = I1[p1];
            const bool take0 = (v0 > v1) || (v0 == v1 && (unsigned)i0 < (unsigned)i1);
            out_vals[obase + round] = take0 ? v0 : v1;
            out_idx [obase + round] = take0 ? i0 : i1;
            p0 += take0 ? 1 : 0;
            p1 += take0 ? 0 : 1;
        }
    }
}

// ---------------- vote kernel (proven R5 structure, fp64 refine) ----------------

__global__ __launch_bounds__(256) void vote_fast(
    const float* __restrict__ cvals,
    const int*   __restrict__ cidx,
    const float* __restrict__ A,
    const float* __restrict__ Bt32,
    const signed char* __restrict__ labT8,
    int*         __restrict__ out)
{
    __shared__ float  sv[CAND];
    __shared__ int    si[CAND];
    __shared__ float  Arow[DIM];
    __shared__ int    sel_i[RSEL];
    __shared__ double cpart[RSEL][8];
    __shared__ double dv[RSEL];
    __shared__ double tvd[K];
    __shared__ int    ti[K];
    __shared__ double wgt[K];

    const int gr = blockIdx.x;
    const int t  = threadIdx.x;

    for (int i = t; i < DIM; i += 256) Arow[i] = A[(size_t)gr * DIM + i];
    for (int e = t; e < CAND; e += 256) {
        sv[e] = cvals[gr * CAND + e];
        si[e] = cidx[gr * CAND + e];
    }
    __syncthreads();

    for (int e = t; e < CAND; e += 256) {
        const float v = sv[e];
        const unsigned id = (unsigned)si[e];
        int rank = 0;
        for (int j = 0; j < CAND; ++j) {
            const float vj = sv[j];
            const unsigned ij = (unsigned)si[j];
            if (vj > v || (vj == v && ij < id)) rank++;
        }
        if (rank < RSEL) sel_i[rank] = (int)id;
    }
    __syncthreads();

    {
        const int cand = t >> 3;
        const int part = t & 7;
        const int idx  = sel_i[cand];
        const int d0   = part * (DIM / 8);
        const float* brow = Bt32 + (size_t)idx * DIM + d0;
        double acc = 0.0;
        #pragma unroll
        for (int q = 0; q < 12; ++q) {
            const float4 b4 = *(const float4*)(brow + q * 4);
            acc = fma((double)Arow[d0 + q*4 + 0], (double)b4.x, acc);
            acc = fma((double)Arow[d0 + q*4 + 1], (double)b4.y, acc);
            acc = fma((double)Arow[d0 + q*4 + 2], (double)b4.z, acc);
            acc = fma((double)Arow[d0 + q*4 + 3], (double)b4.w, acc);
        }
        cpart[cand][part] = acc;
    }
    __syncthreads();

    if (t < RSEL) {
        double s = 0.0;
        #pragma unroll
        for (int p = 0; p < 8; ++p) s += cpart[t][p];
        dv[t] = s;
    }
    __syncthreads();

    if (t < RSEL) {
        const double v = dv[t];
        const unsigned id = (unsigned)sel_i[t];
        int rank = 0;
        for (int j = 0; j < RSEL; ++j) {
            const double vj = dv[j];
            const unsigned ij = (unsigned)sel_i[j];
            if (vj > v || (vj == v && ij < id)) rank++;
        }
        if (rank < K) { tvd[rank] = v; ti[rank] = (int)id; }
    }
    __syncthreads();

    if (t == 0) {
        const double m = tvd[0];
        double e[K];
        double s = 0.0;
        #pragma unroll
        for (int k = 0; k < K; ++k) { e[k] = exp(tvd[k] - m); s += e[k]; }
        const double inv = 1.0 / s;
        #pragma unroll
        for (int k = 0; k < K; ++k) wgt[k] = e[k] * inv;
    }
    __syncthreads();

    int lbl[K];
    #pragma unroll
    for (int k = 0; k < K; ++k) lbl[k] = (int)labT8[(size_t)ti[k] * 256 + t];

    double v[NCLS];
    #pragma unroll
    for (int c = 0; c < NCLS; ++c) v[c] = 0.0;
    #pragma unroll
    for (int k = 0; k < K; ++k) {
        const double wk = wgt[k];
        const int    lk = lbl[k];
        #pragma unroll
        for (int c = 0; c < NCLS; ++c) v[c] += (lk == c) ? wk : 0.0;
    }

    double best = v[0];
    int bi = 0;
    #pragma unroll
    for (int c = 1; c < NCLS; ++c) {
        if (v[c] > best) { best = v[c]; bi = c; }   // strict > : first max, like np.argmax
    }

    const int b  = gr / NPATCH;
    const int p  = gr % NPATCH;
    const int pr = p / 14, pc = p % 14;
    const int i  = t >> 4, j = t & 15;
    out[b * (224 * 224) + (pr * 16 + i) * 224 + (pc * 16 + j)] = bi;
}

extern "C" void kernel_launch(void* const* d_in, const int* in_sizes, int n_in,
                              void* d_out, int out_size, void* d_ws, size_t ws_size,
                              hipStream_t stream)
{
    const float* test_feature   = (const float*)d_in[0];
    const float* train_features = (const float*)d_in[1];
    const int*   train_labels   = (const int*)d_in[2];
    int*         out            = (int*)d_out;

    char* w = (char*)d_ws;                         // ws_size >= 174 MB on this harness (>= WS_NEED)
    uint4*       BtH4  = (uint4*)(w + WS_BTH);
    float*       Bt32  = (float*)(w + WS_BT32);
    signed char* labT8 = (signed char*)(w + WS_LAB);
    uint4*       AH4   = (uint4*)(w + WS_AH);
    float*       cval  = (float*)(w + WS_CVAL);
    int*         cidx  = (int*)(w + WS_CIDX);

    prep_bt<<<NPAD / 64, 256, 0, stream>>>(train_features, BtH4, Bt32);
    prep_a<<<300, 256, 0, stream>>>(test_feature, AH4);
    prep_lab<<<NPAD / 64, 256, 0, stream>>>(train_labels, labT8);

    sim_topk_v6<<<dim3(NSPLIT, NTILES), 256, 0, stream>>>(
        AH4, (const bf16x8*)BtH4, cval, cidx);

    vote_fast<<<NROWS_TOT, 256, 0, stream>>>(cval, cidx, test_feature, Bt32, labT8, out);
}